// Round 1
// baseline (2221.819 us; speedup 1.0000x reference)
//
#include <hip/hip_runtime.h>
#include <math.h>

// Problem constants
#define B_ 256
#define L_ 64
#define R_ 1024
#define A_ 512
#define E_ 1024
#define BR (B_ * R_)

// ---------------------------------------------------------------------------
// Generic tiled SGEMM: C[M,N] = A[M,K] * W[N,K]^T (+ bias[n]) (+ C if acc)
// Requires: M % 64 == 0, N % 64 == 0, K % 16 == 0 (true for all call sites).
// 256 threads, 64x64 tile, 4x4 microtile.
// ---------------------------------------------------------------------------
__global__ __launch_bounds__(256) void sgemm_tn(
    const float* __restrict__ A, const float* __restrict__ W,
    const float* __restrict__ bias, float* __restrict__ C,
    int M, int N, int K, int acc)
{
    __shared__ float As[64][17];
    __shared__ float Ws[64][17];
    const int tid = threadIdx.x;
    const int tx = tid & 15, ty = tid >> 4;
    const int bm = blockIdx.y * 64, bn = blockIdx.x * 64;
    const int lr = tid >> 2;          // 0..63 row within tile
    const int lk = (tid & 3) << 2;    // 0,4,8,12 k offset
    const float* Ap = A + (size_t)(bm + lr) * K + lk;
    const float* Wp = W + (size_t)(bn + lr) * K + lk;

    float c[4][4] = {};

    for (int k0 = 0; k0 < K; k0 += 16) {
        float4 av = *(const float4*)(Ap + k0);
        float4 wv = *(const float4*)(Wp + k0);
        As[lr][lk + 0] = av.x; As[lr][lk + 1] = av.y;
        As[lr][lk + 2] = av.z; As[lr][lk + 3] = av.w;
        Ws[lr][lk + 0] = wv.x; Ws[lr][lk + 1] = wv.y;
        Ws[lr][lk + 2] = wv.z; Ws[lr][lk + 3] = wv.w;
        __syncthreads();
        #pragma unroll
        for (int kk = 0; kk < 16; ++kk) {
            float a[4], b[4];
            #pragma unroll
            for (int i = 0; i < 4; ++i) a[i] = As[ty * 4 + i][kk];
            #pragma unroll
            for (int j = 0; j < 4; ++j) b[j] = Ws[tx * 4 + j][kk];
            #pragma unroll
            for (int i = 0; i < 4; ++i)
                #pragma unroll
                for (int j = 0; j < 4; ++j)
                    c[i][j] += a[i] * b[j];
        }
        __syncthreads();
    }

    #pragma unroll
    for (int i = 0; i < 4; ++i) {
        int m = bm + ty * 4 + i;
        #pragma unroll
        for (int j = 0; j < 4; ++j) {
            int n = bn + tx * 4 + j;
            float v = c[i][j];
            if (bias) v += bias[n];
            size_t off = (size_t)m * N + n;
            if (acc) v += C[off];
            C[off] = v;
        }
    }
}

// ---------------------------------------------------------------------------
// env = concat([prev_h, fc_feats, xt], axis=1)  -> [B, 3072]
// ---------------------------------------------------------------------------
__global__ void build_env(const float* __restrict__ prev_h,
                          const float* __restrict__ fc,
                          const float* __restrict__ xt,
                          float* __restrict__ env)
{
    int idx = blockIdx.x * blockDim.x + threadIdx.x;   // B * 3072
    int b = idx / 3072, k = idx - b * 3072;
    float v;
    if (k < R_)             v = prev_h[b * R_ + k];
    else if (k < 2 * R_)    v = fc[b * R_ + (k - R_)];
    else                    v = xt[b * E_ + (k - 2 * R_)];
    env[idx] = v;
}

// lang_in = concat([output_feats, h_vis], axis=1) -> [B, 2048]
__global__ void build_lang_in(const float* __restrict__ of,
                              const float* __restrict__ hv,
                              float* __restrict__ li)
{
    int idx = blockIdx.x * blockDim.x + threadIdx.x;   // B * 2048
    int b = idx >> 11, k = idx & 2047;
    li[idx] = (k < R_) ? of[b * R_ + k] : hv[b * R_ + (k - R_)];
}

// feats3 = stack([single_feat, comp_feat, fc_feats], axis=1) -> [B, 3, R]
__global__ void build_feats3(const float* __restrict__ sf,
                             const float* __restrict__ cf,
                             const float* __restrict__ fc,
                             float* __restrict__ f3)
{
    int idx = blockIdx.x * blockDim.x + threadIdx.x;   // B * 3 * R
    int d = idx % R_;
    int t = idx / R_;
    int j = t % 3, b = t / 3;
    float v;
    if (j == 0)      v = sf[b * R_ + d];
    else if (j == 1) v = cf[b * R_ + d];
    else             v = fc[b * R_ + d];
    f3[idx] = v;
}

// ---------------------------------------------------------------------------
// LSTM pointwise: gates [B,4R] (i,f,g,o), c_prev [B,R] -> h, c
// ---------------------------------------------------------------------------
__device__ __forceinline__ float sigm_(float x) { return 1.f / (1.f + __expf(-x)); }

__global__ void lstm_pointwise(const float* __restrict__ gates,
                               const float* __restrict__ c_prev,
                               float* __restrict__ h_out,
                               float* __restrict__ h_out2,
                               float* __restrict__ c_out)
{
    int idx = blockIdx.x * blockDim.x + threadIdx.x;   // B * R
    int b = idx >> 10, r = idx & (R_ - 1);
    const float* g = gates + (size_t)b * 4 * R_;
    float ig = g[r], fg = g[R_ + r], gg = g[2 * R_ + r], og = g[3 * R_ + r];
    float c2 = sigm_(fg) * c_prev[idx] + sigm_(ig) * tanhf(gg);
    float h2 = sigm_(og) * tanhf(c2);
    c_out[idx] = c2;
    h_out[idx] = h2;
    if (h_out2) h_out2[idx] = h2;
}

// ---------------------------------------------------------------------------
// logits[b,l] = sum_a tanh(base[b,a] + sign*proj[b,l,a]) * wa[a] + wa_b
// one wave per (b,l); requires (B*L) % 4 == 0
// ---------------------------------------------------------------------------
__global__ __launch_bounds__(256) void attn_logits(
    const float* __restrict__ base, const float* __restrict__ proj,
    const float* __restrict__ wa, const float* __restrict__ wa_b,
    float* __restrict__ logits, int L, float sign)
{
    int idx = blockIdx.x * 4 + (threadIdx.x >> 6);
    int lane = threadIdx.x & 63;
    int b = idx / L;
    const float* p = proj + (size_t)idx * A_;
    const float* bs = base + (size_t)b * A_;
    float acc = 0.f;
    #pragma unroll
    for (int a0 = 0; a0 < A_; a0 += 64) {
        int a = a0 + lane;
        acc += tanhf(bs[a] + sign * p[a]) * wa[a];
    }
    #pragma unroll
    for (int off = 32; off > 0; off >>= 1) acc += __shfl_xor(acc, off);
    if (lane == 0) logits[idx] = acc + wa_b[0];
}

// softmax over L (<=64) per row; one wave per row; rows % 4 == 0
__global__ __launch_bounds__(256) void softmax_rows(
    const float* __restrict__ logits, float* __restrict__ w, int L)
{
    int row = blockIdx.x * 4 + (threadIdx.x >> 6);
    int lane = threadIdx.x & 63;
    float v = (lane < L) ? logits[row * L + lane] : -INFINITY;
    float m = v;
    #pragma unroll
    for (int off = 32; off > 0; off >>= 1) m = fmaxf(m, __shfl_xor(m, off));
    float e = (lane < L) ? __expf(v - m) : 0.f;
    float s = e;
    #pragma unroll
    for (int off = 32; off > 0; off >>= 1) s += __shfl_xor(s, off);
    if (lane < L) w[row * L + lane] = e / s;
}

// out[b,d] = sum_l w[b,l]*V[b,l,d]        (addfrom == nullptr)
//          = addfrom[b,d] - sum_l ...     (comp attention)
__global__ void weighted_sum(const float* __restrict__ w,
                             const float* __restrict__ V,
                             const float* __restrict__ addfrom,
                             float* __restrict__ out, int L, int D)
{
    int idx = blockIdx.x * blockDim.x + threadIdx.x;   // B * D
    int b = idx / D, d = idx - b * D;
    const float* vp = V + (size_t)b * L * D + d;
    const float* wp = w + b * L;
    float acc = 0.f;
    for (int l = 0; l < L; ++l) acc += wp[l] * vp[(size_t)l * D];
    out[idx] = addfrom ? (addfrom[idx] - acc) : acc;
}

// ---------------------------------------------------------------------------
extern "C" void kernel_launch(void* const* d_in, const int* in_sizes, int n_in,
                              void* d_out, int out_size, void* d_ws, size_t ws_size,
                              hipStream_t stream)
{
    const float* xt      = (const float*)d_in[0];
    const float* fc      = (const float*)d_in[1];
    const float* roi     = (const float*)d_in[2];
    const float* p_roi   = (const float*)d_in[3];
    const float* ctxf    = (const float*)d_in[4];
    const float* sh      = (const float*)d_in[5];   // state_h [2,B,R]
    const float* sc      = (const float*)d_in[6];   // state_c [2,B,R]
    const float* W_ih_v  = (const float*)d_in[7];
    const float* W_hh_v  = (const float*)d_in[8];
    const float* b_ih_v  = (const float*)d_in[9];
    const float* b_hh_v  = (const float*)d_in[10];
    const float* W_ih_l  = (const float*)d_in[11];
    const float* W_hh_l  = (const float*)d_in[12];
    const float* b_ih_l  = (const float*)d_in[13];
    const float* b_hh_l  = (const float*)d_in[14];
    const float* sp_wh_w = (const float*)d_in[15];
    const float* sp_wh_b = (const float*)d_in[16];
    const float* sp_wa_w = (const float*)d_in[17];
    const float* sp_wa_b = (const float*)d_in[18];
    const float* ctx_wh_w= (const float*)d_in[19];
    const float* ctx_wh_b= (const float*)d_in[20];
    const float* ctx_wv_w= (const float*)d_in[21];
    const float* ctx_wv_b= (const float*)d_in[22];
    const float* ctx_wa_w= (const float*)d_in[23];
    const float* ctx_wa_b= (const float*)d_in[24];
    const float* cmp_wh_w= (const float*)d_in[25];
    const float* cmp_wh_b= (const float*)d_in[26];
    const float* cmp_wv_w= (const float*)d_in[27];
    const float* cmp_wv_b= (const float*)d_in[28];
    const float* cmp_wa_w= (const float*)d_in[29];
    const float* cmp_wa_b= (const float*)d_in[30];
    const float* out_wv_w= (const float*)d_in[31];
    const float* out_wv_b= (const float*)d_in[32];
    const float* out_wh_w= (const float*)d_in[33];
    const float* out_wh_b= (const float*)d_in[34];
    const float* out_wa_w= (const float*)d_in[35];
    const float* out_wa_b= (const float*)d_in[36];

    float* out = (float*)d_out;
    // output layout: [h_lang | new_h(h_vis,h_lang) | new_c(c_vis,c_lang) | output_feats]
    float* h_vis    = out + BR;
    float* h_lang   = out;             // also duplicated at out + 2*BR
    float* h_lang2  = out + 2 * BR;
    float* c_vis    = out + 3 * BR;
    float* c_lang   = out + 4 * BR;
    float* out_feats= out + 5 * BR;

    float* ws = (float*)d_ws;
    float* env        = ws;                              // B*3072
    float* gates      = env + (size_t)B_ * 3072;         // B*4096 (reused)
    float* hproj_sp   = gates + (size_t)B_ * 4096;       // B*A
    float* hproj_ctx  = hproj_sp + (size_t)B_ * A_;
    float* base_cmp   = hproj_ctx + (size_t)B_ * A_;
    float* hproj_out  = base_cmp + (size_t)B_ * A_;
    float* proj_big   = hproj_out + (size_t)B_ * A_;     // B*L*A (reused)
    float* logits     = proj_big + (size_t)B_ * L_ * A_; // B*L
    float* attw       = logits + B_ * L_;
    float* single_feat= attw + B_ * L_;                  // B*R
    float* context_feat = single_feat + BR;
    float* comp_feat  = context_feat + BR;
    float* feats3     = comp_feat + BR;                  // B*3*R
    float* f3_proj    = feats3 + (size_t)B_ * 3 * R_;    // B*3*A
    float* lang_in    = f3_proj + (size_t)B_ * 3 * A_;   // B*2R

    const dim3 blk(256);

    // ---- visual LSTM ----
    build_env<<<dim3(B_ * 3072 / 256), blk, 0, stream>>>(sh + BR, fc, xt, env);
    sgemm_tn<<<dim3(4096 / 64, B_ / 64), blk, 0, stream>>>(env, W_ih_v, b_ih_v, gates, B_, 4096, 3072, 0);
    sgemm_tn<<<dim3(4096 / 64, B_ / 64), blk, 0, stream>>>(sh, W_hh_v, b_hh_v, gates, B_, 4096, 1024, 1);
    lstm_pointwise<<<dim3(BR / 256), blk, 0, stream>>>(gates, sc, h_vis, nullptr, c_vis);

    // ---- SingleSP ----
    sgemm_tn<<<dim3(A_ / 64, B_ / 64), blk, 0, stream>>>(h_vis, sp_wh_w, sp_wh_b, hproj_sp, B_, A_, R_, 0);
    attn_logits<<<dim3(B_ * L_ / 4), blk, 0, stream>>>(hproj_sp, p_roi, sp_wa_w, sp_wa_b, logits, L_, 1.f);
    softmax_rows<<<dim3(B_ / 4), blk, 0, stream>>>(logits, attw, L_);
    weighted_sum<<<dim3(BR / 256), blk, 0, stream>>>(attw, roi, nullptr, single_feat, L_, R_);

    // ---- ContextSP ----
    sgemm_tn<<<dim3(A_ / 64, B_ / 64), blk, 0, stream>>>(h_vis, ctx_wh_w, ctx_wh_b, hproj_ctx, B_, A_, R_, 0);
    sgemm_tn<<<dim3(A_ / 64, B_ * L_ / 64), blk, 0, stream>>>(ctxf, ctx_wv_w, ctx_wv_b, proj_big, B_ * L_, A_, R_, 0);
    attn_logits<<<dim3(B_ * L_ / 4), blk, 0, stream>>>(hproj_ctx, proj_big, ctx_wa_w, ctx_wa_b, logits, L_, 1.f);
    softmax_rows<<<dim3(B_ / 4), blk, 0, stream>>>(logits, attw, L_);
    weighted_sum<<<dim3(BR / 256), blk, 0, stream>>>(attw, ctxf, nullptr, context_feat, L_, R_);

    // ---- CompSP ----
    // base_cmp = h_vis@cmp_wh^T + cmp_wh_b + context_feat@cmp_wv^T + cmp_wv_b
    sgemm_tn<<<dim3(A_ / 64, B_ / 64), blk, 0, stream>>>(h_vis, cmp_wh_w, cmp_wh_b, base_cmp, B_, A_, R_, 0);
    sgemm_tn<<<dim3(A_ / 64, B_ / 64), blk, 0, stream>>>(context_feat, cmp_wv_w, cmp_wv_b, base_cmp, B_, A_, R_, 1);
    // proj_big = roi@cmp_wv^T (no bias); rel_proj[b,l]= base_cmp[b]-proj_big[b,l] (sign=-1)
    sgemm_tn<<<dim3(A_ / 64, B_ * L_ / 64), blk, 0, stream>>>(roi, cmp_wv_w, nullptr, proj_big, B_ * L_, A_, R_, 0);
    attn_logits<<<dim3(B_ * L_ / 4), blk, 0, stream>>>(base_cmp, proj_big, cmp_wa_w, cmp_wa_b, logits, L_, -1.f);
    softmax_rows<<<dim3(B_ / 4), blk, 0, stream>>>(logits, attw, L_);
    // comp_feat = context_feat - sum_l w*roi  (softmax weights sum to 1)
    weighted_sum<<<dim3(BR / 256), blk, 0, stream>>>(attw, roi, context_feat, comp_feat, L_, R_);

    // ---- OutputSP ----
    build_feats3<<<dim3(B_ * 3 * R_ / 256), blk, 0, stream>>>(single_feat, comp_feat, fc, feats3);
    sgemm_tn<<<dim3(A_ / 64, B_ * 3 / 64), blk, 0, stream>>>(feats3, out_wv_w, out_wv_b, f3_proj, B_ * 3, A_, R_, 0);
    sgemm_tn<<<dim3(A_ / 64, B_ / 64), blk, 0, stream>>>(h_vis, out_wh_w, out_wh_b, hproj_out, B_, A_, R_, 0);
    attn_logits<<<dim3(B_ * 3 / 4), blk, 0, stream>>>(hproj_out, f3_proj, out_wa_w, out_wa_b, logits, 3, 1.f);
    softmax_rows<<<dim3(B_ / 4), blk, 0, stream>>>(logits, attw, 3);
    weighted_sum<<<dim3(BR / 256), blk, 0, stream>>>(attw, feats3, nullptr, out_feats, 3, R_);

    // ---- language LSTM ----
    build_lang_in<<<dim3(B_ * 2048 / 256), blk, 0, stream>>>(out_feats, h_vis, lang_in);
    sgemm_tn<<<dim3(4096 / 64, B_ / 64), blk, 0, stream>>>(lang_in, W_ih_l, b_ih_l, gates, B_, 4096, 2048, 0);
    sgemm_tn<<<dim3(4096 / 64, B_ / 64), blk, 0, stream>>>(sh + BR, W_hh_l, b_hh_l, gates, B_, 4096, 1024, 1);
    lstm_pointwise<<<dim3(BR / 256), blk, 0, stream>>>(gates, sc + BR, h_lang, h_lang2, c_lang);
}

// Round 2
// 718.345 us; speedup vs baseline: 3.0930x; 3.0930x over previous
//
#include <hip/hip_runtime.h>
#include <hip/hip_bf16.h>
#include <math.h>

#define B_ 256
#define L_ 64
#define R_ 1024
#define A_ 512
#define E_ 1024
#define BR (B_ * R_)

typedef __attribute__((ext_vector_type(8))) short short8;
typedef __attribute__((ext_vector_type(4))) float f32x4;

__device__ __forceinline__ unsigned int pkbf(float x, float y) {
    union { __hip_bfloat162 h; unsigned int u; } cv;
    cv.h = __float22bfloat162_rn(make_float2(x, y));
    return cv.u;
}

__device__ __forceinline__ float tanh_fast(float x) {
    return 1.f - 2.f / (1.f + __expf(2.f * x));
}
__device__ __forceinline__ float sigm_(float x) { return 1.f / (1.f + __expf(-x)); }

// ---------------------------------------------------------------------------
// bf16 MFMA GEMM core: 128x128 tile of C = A[M,K] * W[N,K]^T
// fp32->bf16 conversion fused into LDS staging; XOR-swizzled 16B chunks.
// ---------------------------------------------------------------------------
__device__ __forceinline__ void mm_core(const float* __restrict__ Abm, int lda,
                                        const float* __restrict__ Wbn, int ldw,
                                        int K, f32x4 acc[4][4])
{
    __shared__ unsigned int As[2048];   // 128 rows x 32 bf16
    __shared__ unsigned int Ws[2048];

    const int t = threadIdx.x;
    const int srow = t >> 3;
    const int sub = t & 7;
    const int q = sub >> 1, half = sub & 1;
    const int csw = (q ^ ((srow >> 1) & 3));
    int sidx[4];
    const float* pa[4];
    const float* pw[4];
    #pragma unroll
    for (int i = 0; i < 4; ++i) {
        int row = srow + 32 * i;
        sidx[i] = row * 16 + csw * 4 + half * 2;
        pa[i] = Abm + (size_t)row * lda + sub * 4;
        pw[i] = Wbn + (size_t)row * ldw + sub * 4;
    }

    const int w = t >> 6, lane = t & 63;
    const int m0 = (w >> 1) * 64, n0 = (w & 1) * 64;
    const int lrow = lane & 15, quad = lane >> 4;
    int aidx[4], widx[4];
    #pragma unroll
    for (int i = 0; i < 4; ++i) {
        int ra = m0 + i * 16 + lrow;
        aidx[i] = ra * 16 + ((quad ^ ((ra >> 1) & 3)) << 2);
        int rw = n0 + i * 16 + lrow;
        widx[i] = rw * 16 + ((quad ^ ((rw >> 1) & 3)) << 2);
    }

    for (int k0 = 0; k0 < K; k0 += 32) {
        #pragma unroll
        for (int i = 0; i < 4; ++i) {
            float4 av = *(const float4*)pa[i]; pa[i] += 32;
            float4 wv = *(const float4*)pw[i]; pw[i] += 32;
            *(uint2*)(As + sidx[i]) = make_uint2(pkbf(av.x, av.y), pkbf(av.z, av.w));
            *(uint2*)(Ws + sidx[i]) = make_uint2(pkbf(wv.x, wv.y), pkbf(wv.z, wv.w));
        }
        __syncthreads();
        short8 af[4], wf[4];
        #pragma unroll
        for (int i = 0; i < 4; ++i) {
            af[i] = *(const short8*)(As + aidx[i]);
            wf[i] = *(const short8*)(Ws + widx[i]);
        }
        #pragma unroll
        for (int mt = 0; mt < 4; ++mt)
            #pragma unroll
            for (int nt = 0; nt < 4; ++nt)
                acc[mt][nt] = __builtin_amdgcn_mfma_f32_16x16x32_bf16(
                    af[mt], wf[nt], acc[mt][nt], 0, 0, 0);
        __syncthreads();
    }
}

__device__ __forceinline__ void mm_store(f32x4 acc[4][4], float* Cbm, int ldc,
                                         int bn, const float* bias)
{
    const int t = threadIdx.x;
    const int w = t >> 6, lane = t & 63;
    const int m0 = (w >> 1) * 64, n0 = (w & 1) * 64;
    const int lrow = lane & 15, quad = lane >> 4;
    #pragma unroll
    for (int nt = 0; nt < 4; ++nt) {
        int col = bn + n0 + nt * 16 + lrow;
        float bv = bias ? bias[col] : 0.f;
        #pragma unroll
        for (int mt = 0; mt < 4; ++mt) {
            int rbase = m0 + mt * 16 + quad * 4;
            #pragma unroll
            for (int r = 0; r < 4; ++r)
                Cbm[(size_t)(rbase + r) * ldc + col] = acc[mt][nt][r] + bv;
        }
    }
}

__global__ __launch_bounds__(256) void mm_plain(
    const float* __restrict__ A, int lda, const float* __restrict__ W, int ldw,
    const float* __restrict__ bias, float* __restrict__ C, int ldc, int K,
    int M1, const float* __restrict__ A2, const float* __restrict__ bias2,
    float* __restrict__ C2)
{
    int bm = blockIdx.y * 128, bn = blockIdx.x * 128;
    const float* Abm; float* Cbm; const float* bs;
    if (bm < M1) {
        Abm = A + (size_t)bm * lda; Cbm = C + (size_t)bm * ldc; bs = bias;
    } else {
        int bm2 = bm - M1;
        Abm = A2 + (size_t)bm2 * lda; Cbm = C2 + (size_t)bm2 * ldc; bs = bias2;
    }
    f32x4 acc[4][4];
    #pragma unroll
    for (int i = 0; i < 4; ++i)
        #pragma unroll
        for (int j = 0; j < 4; ++j) acc[i][j] = (f32x4)0.f;
    mm_core(Abm, lda, W + (size_t)bn * ldw, ldw, K, acc);
    mm_store(acc, Cbm, ldc, bn, bs);
}

struct P4 { const float* W[4]; const float* bias[4]; };
__global__ __launch_bounds__(256) void mm_batch4(
    const float* __restrict__ A, int lda, P4 p, float* __restrict__ Cbase,
    int ldc, int K, int zstride)
{
    int z = blockIdx.z;
    int bm = blockIdx.y * 128, bn = blockIdx.x * 128;
    f32x4 acc[4][4];
    #pragma unroll
    for (int i = 0; i < 4; ++i)
        #pragma unroll
        for (int j = 0; j < 4; ++j) acc[i][j] = (f32x4)0.f;
    mm_core(A + (size_t)bm * lda, lda, p.W[z] + (size_t)bn * lda, lda, K, acc);
    mm_store(acc, Cbase + (size_t)z * zstride + (size_t)bm * ldc, ldc, bn, p.bias[z]);
}

struct C4 { const float* A[4]; const float* W[4]; int lda[4]; int ldw[4]; };
__global__ __launch_bounds__(256) void mm_chunks(
    C4 p, float* __restrict__ Cbase, int ldc, int K, int zstride)
{
    int z = blockIdx.z;
    int bm = blockIdx.y * 128, bn = blockIdx.x * 128;
    f32x4 acc[4][4];
    #pragma unroll
    for (int i = 0; i < 4; ++i)
        #pragma unroll
        for (int j = 0; j < 4; ++j) acc[i][j] = (f32x4)0.f;
    mm_core(p.A[z] + (size_t)bm * p.lda[z], p.lda[z],
            p.W[z] + (size_t)bn * p.ldw[z], p.ldw[z], K, acc);
    mm_store(acc, Cbase + (size_t)z * zstride + (size_t)bm * ldc, ldc, bn, nullptr);
}

// ---------------------------------------------------------------------------
__global__ void build_env(const float* __restrict__ prev_h,
                          const float* __restrict__ fc,
                          const float* __restrict__ xt,
                          float* __restrict__ env)
{
    int idx = blockIdx.x * blockDim.x + threadIdx.x;
    int b = idx / 3072, k = idx - b * 3072;
    float v;
    if (k < R_)          v = prev_h[b * R_ + k];
    else if (k < 2 * R_) v = fc[b * R_ + (k - R_)];
    else                 v = xt[b * E_ + (k - 2 * R_)];
    env[idx] = v;
}

__global__ void build_lang_in(const float* __restrict__ of,
                              const float* __restrict__ hv,
                              float* __restrict__ li)
{
    int idx = blockIdx.x * blockDim.x + threadIdx.x;
    int b = idx >> 11, k = idx & 2047;
    li[idx] = (k < R_) ? of[b * R_ + k] : hv[b * R_ + (k - R_)];
}

__global__ void build_feats3(const float* __restrict__ sf,
                             const float* __restrict__ cf,
                             const float* __restrict__ fc,
                             float* __restrict__ f3)
{
    int idx = blockIdx.x * blockDim.x + threadIdx.x;
    int d = idx % R_;
    int tt = idx / R_;
    int j = tt % 3, b = tt / 3;
    float v;
    if (j == 0)      v = sf[b * R_ + d];
    else if (j == 1) v = cf[b * R_ + d];
    else             v = fc[b * R_ + d];
    f3[idx] = v;
}

__global__ void lstm_pw(const float* __restrict__ gp, int P,
                        const float* __restrict__ b_ih, const float* __restrict__ b_hh,
                        const float* __restrict__ c_prev,
                        float* __restrict__ h_out, float* __restrict__ h_out2,
                        float* __restrict__ c_out)
{
    int idx = blockIdx.x * blockDim.x + threadIdx.x;
    int b = idx >> 10, r = idx & (R_ - 1);
    float g[4];
    #pragma unroll
    for (int gi = 0; gi < 4; ++gi) {
        int o = gi * R_ + r;
        float s = b_ih[o] + b_hh[o];
        for (int p = 0; p < P; ++p)
            s += gp[(size_t)p * B_ * 4096 + (size_t)b * 4096 + o];
        g[gi] = s;
    }
    float c2 = sigm_(g[1]) * c_prev[idx] + sigm_(g[0]) * tanh_fast(g[2]);
    float h2 = sigm_(g[3]) * tanh_fast(c2);
    c_out[idx] = c2;
    h_out[idx] = h2;
    if (h_out2) h_out2[idx] = h2;
}

__global__ __launch_bounds__(256) void attn_logits(
    const float* __restrict__ base, const float* __restrict__ base2,
    const float* __restrict__ proj,
    const float* __restrict__ wa, const float* __restrict__ wa_b,
    float* __restrict__ logits, int L, float sign)
{
    int idx = blockIdx.x * 4 + (threadIdx.x >> 6);
    int lane = threadIdx.x & 63;
    int b = idx / L;
    const float* p = proj + (size_t)idx * A_;
    const float* bs = base + (size_t)b * A_;
    const float* bs2 = base2 ? base2 + (size_t)b * A_ : nullptr;
    float acc = 0.f;
    #pragma unroll
    for (int a0 = 0; a0 < A_; a0 += 64) {
        int a = a0 + lane;
        float bb = bs[a];
        if (bs2) bb += bs2[a];
        acc += tanh_fast(bb + sign * p[a]) * wa[a];
    }
    #pragma unroll
    for (int off = 32; off > 0; off >>= 1) acc += __shfl_xor(acc, off);
    if (lane == 0) logits[idx] = acc + wa_b[0];
}

__global__ __launch_bounds__(256) void softmax_rows(
    const float* __restrict__ logits, float* __restrict__ w, int L)
{
    int row = blockIdx.x * 4 + (threadIdx.x >> 6);
    int lane = threadIdx.x & 63;
    float v = (lane < L) ? logits[row * L + lane] : -INFINITY;
    float m = v;
    #pragma unroll
    for (int off = 32; off > 0; off >>= 1) m = fmaxf(m, __shfl_xor(m, off));
    float e = (lane < L) ? __expf(v - m) : 0.f;
    float s = e;
    #pragma unroll
    for (int off = 32; off > 0; off >>= 1) s += __shfl_xor(s, off);
    if (lane < L) w[row * L + lane] = e / s;
}

__global__ void weighted_sum(const float* __restrict__ w,
                             const float* __restrict__ V,
                             const float* __restrict__ addfrom,
                             float* __restrict__ out, int L, int D)
{
    int idx = blockIdx.x * blockDim.x + threadIdx.x;
    int b = idx / D, d = idx - b * D;
    const float* vp = V + (size_t)b * L * D + d;
    const float* wp = w + b * L;
    float acc = 0.f;
    for (int l = 0; l < L; ++l) acc += wp[l] * vp[(size_t)l * D];
    out[idx] = addfrom ? (addfrom[idx] - acc) : acc;
}

// ---------------------------------------------------------------------------
extern "C" void kernel_launch(void* const* d_in, const int* in_sizes, int n_in,
                              void* d_out, int out_size, void* d_ws, size_t ws_size,
                              hipStream_t stream)
{
    const float* xt      = (const float*)d_in[0];
    const float* fc      = (const float*)d_in[1];
    const float* roi     = (const float*)d_in[2];
    const float* p_roi   = (const float*)d_in[3];
    const float* ctxf    = (const float*)d_in[4];
    const float* sh      = (const float*)d_in[5];
    const float* sc      = (const float*)d_in[6];
    const float* W_ih_v  = (const float*)d_in[7];
    const float* W_hh_v  = (const float*)d_in[8];
    const float* b_ih_v  = (const float*)d_in[9];
    const float* b_hh_v  = (const float*)d_in[10];
    const float* W_ih_l  = (const float*)d_in[11];
    const float* W_hh_l  = (const float*)d_in[12];
    const float* b_ih_l  = (const float*)d_in[13];
    const float* b_hh_l  = (const float*)d_in[14];
    const float* sp_wh_w = (const float*)d_in[15];
    const float* sp_wh_b = (const float*)d_in[16];
    const float* sp_wa_w = (const float*)d_in[17];
    const float* sp_wa_b = (const float*)d_in[18];
    const float* ctx_wh_w= (const float*)d_in[19];
    const float* ctx_wh_b= (const float*)d_in[20];
    const float* ctx_wv_w= (const float*)d_in[21];
    const float* ctx_wv_b= (const float*)d_in[22];
    const float* ctx_wa_w= (const float*)d_in[23];
    const float* ctx_wa_b= (const float*)d_in[24];
    const float* cmp_wh_w= (const float*)d_in[25];
    const float* cmp_wh_b= (const float*)d_in[26];
    const float* cmp_wv_w= (const float*)d_in[27];
    const float* cmp_wv_b= (const float*)d_in[28];
    const float* cmp_wa_w= (const float*)d_in[29];
    const float* cmp_wa_b= (const float*)d_in[30];
    const float* out_wv_w= (const float*)d_in[31];
    const float* out_wv_b= (const float*)d_in[32];
    const float* out_wh_w= (const float*)d_in[33];
    const float* out_wh_b= (const float*)d_in[34];
    const float* out_wa_w= (const float*)d_in[35];
    const float* out_wa_b= (const float*)d_in[36];

    float* out = (float*)d_out;
    float* h_vis    = out + BR;
    float* h_lang   = out;
    float* h_lang2  = out + 2 * BR;
    float* c_vis    = out + 3 * BR;
    float* c_lang   = out + 4 * BR;
    float* out_feats= out + 5 * BR;

    float* ws = (float*)d_ws;
    float* env        = ws;
    float* proj_big   = env + (size_t)B_ * 3072;
    float* gates      = proj_big;                          // overlay (lifetimes disjoint)
    float* hproj4     = proj_big + (size_t)16384 * A_;
    float* base_cmp2  = hproj4 + (size_t)4 * B_ * A_;
    float* logits     = base_cmp2 + (size_t)B_ * A_;
    float* attw       = logits + B_ * L_;
    float* single_feat= attw + B_ * L_;
    float* context_feat = single_feat + BR;
    float* comp_feat  = context_feat + BR;
    float* feats3     = comp_feat + BR;
    float* f3_proj    = feats3 + (size_t)B_ * 3 * R_;
    float* lang_in    = f3_proj + (size_t)768 * A_;

    const dim3 blk(256);
    const int HUGE_M = 1 << 30;

    build_env<<<dim3(B_ * 3072 / 256), blk, 0, stream>>>(sh + BR, fc, xt, env);
    {
        C4 cv;
        cv.A[0] = env;        cv.lda[0] = 3072; cv.W[0] = W_ih_v;        cv.ldw[0] = 3072;
        cv.A[1] = env + 1024; cv.lda[1] = 3072; cv.W[1] = W_ih_v + 1024; cv.ldw[1] = 3072;
        cv.A[2] = env + 2048; cv.lda[2] = 3072; cv.W[2] = W_ih_v + 2048; cv.ldw[2] = 3072;
        cv.A[3] = sh;         cv.lda[3] = 1024; cv.W[3] = W_hh_v;        cv.ldw[3] = 1024;
        mm_chunks<<<dim3(32, 2, 4), blk, 0, stream>>>(cv, gates, 4096, 1024, B_ * 4096);
    }
    lstm_pw<<<dim3(BR / 256), blk, 0, stream>>>(gates, 4, b_ih_v, b_hh_v, sc, h_vis, nullptr, c_vis);

    {
        P4 p;
        p.W[0] = sp_wh_w;  p.bias[0] = sp_wh_b;
        p.W[1] = ctx_wh_w; p.bias[1] = ctx_wh_b;
        p.W[2] = cmp_wh_w; p.bias[2] = cmp_wh_b;
        p.W[3] = out_wh_w; p.bias[3] = out_wh_b;
        mm_batch4<<<dim3(4, 2, 4), blk, 0, stream>>>(h_vis, 1024, p, hproj4, 512, 1024, B_ * A_);
    }

    attn_logits<<<dim3(B_ * L_ / 4), blk, 0, stream>>>(hproj4, nullptr, p_roi, sp_wa_w, sp_wa_b, logits, L_, 1.f);
    softmax_rows<<<dim3(B_ / 4), blk, 0, stream>>>(logits, attw, L_);
    weighted_sum<<<dim3(BR / 256), blk, 0, stream>>>(attw, roi, nullptr, single_feat, L_, R_);

    mm_plain<<<dim3(4, 128), blk, 0, stream>>>(ctxf, 1024, ctx_wv_w, 1024, ctx_wv_b,
                                               proj_big, 512, 1024, HUGE_M, nullptr, nullptr, nullptr);
    attn_logits<<<dim3(B_ * L_ / 4), blk, 0, stream>>>(hproj4 + (size_t)B_ * A_, nullptr, proj_big,
                                                       ctx_wa_w, ctx_wa_b, logits, L_, 1.f);
    softmax_rows<<<dim3(B_ / 4), blk, 0, stream>>>(logits, attw, L_);
    weighted_sum<<<dim3(BR / 256), blk, 0, stream>>>(attw, ctxf, nullptr, context_feat, L_, R_);

    mm_plain<<<dim3(4, 130), blk, 0, stream>>>(roi, 1024, cmp_wv_w, 1024, nullptr,
                                               proj_big, 512, 1024, 16384,
                                               context_feat, cmp_wv_b, base_cmp2);
    attn_logits<<<dim3(B_ * L_ / 4), blk, 0, stream>>>(hproj4 + (size_t)2 * B_ * A_, base_cmp2, proj_big,
                                                       cmp_wa_w, cmp_wa_b, logits, L_, -1.f);
    softmax_rows<<<dim3(B_ / 4), blk, 0, stream>>>(logits, attw, L_);
    weighted_sum<<<dim3(BR / 256), blk, 0, stream>>>(attw, roi, context_feat, comp_feat, L_, R_);

    build_feats3<<<dim3(B_ * 3 * R_ / 256), blk, 0, stream>>>(single_feat, comp_feat, fc, feats3);
    mm_plain<<<dim3(4, 6), blk, 0, stream>>>(feats3, 1024, out_wv_w, 1024, out_wv_b,
                                             f3_proj, 512, 1024, HUGE_M, nullptr, nullptr, nullptr);
    attn_logits<<<dim3(B_ * 3 / 4), blk, 0, stream>>>(hproj4 + (size_t)3 * B_ * A_, nullptr, f3_proj,
                                                      out_wa_w, out_wa_b, logits, 3, 1.f);
    softmax_rows<<<dim3(B_ / 4), blk, 0, stream>>>(logits, attw, 3);
    weighted_sum<<<dim3(BR / 256), blk, 0, stream>>>(attw, feats3, nullptr, out_feats, 3, R_);

    build_lang_in<<<dim3(B_ * 2048 / 256), blk, 0, stream>>>(out_feats, h_vis, lang_in);
    {
        C4 cl;
        cl.A[0] = lang_in;        cl.lda[0] = 2048; cl.W[0] = W_ih_l;        cl.ldw[0] = 2048;
        cl.A[1] = lang_in + 1024; cl.lda[1] = 2048; cl.W[1] = W_ih_l + 1024; cl.ldw[1] = 2048;
        cl.A[2] = sh + BR;        cl.lda[2] = 1024; cl.W[2] = W_hh_l;        cl.ldw[2] = 1024;
        cl.A[3] = sh + BR;        cl.lda[3] = 1024; cl.W[3] = W_hh_l;        cl.ldw[3] = 1024;
        mm_chunks<<<dim3(32, 2, 3), blk, 0, stream>>>(cl, gates, 4096, 1024, B_ * 4096);
    }
    lstm_pw<<<dim3(BR / 256), blk, 0, stream>>>(gates, 3, b_ih_l, b_hh_l, sc + BR, h_lang, h_lang2, c_lang);
}

// Round 3
// 587.512 us; speedup vs baseline: 3.7817x; 1.2227x over previous
//
#include <hip/hip_runtime.h>
#include <hip/hip_bf16.h>
#include <math.h>

#define B_ 256
#define L_ 64
#define R_ 1024
#define A_ 512
#define E_ 1024
#define BR (B_ * R_)

typedef __attribute__((ext_vector_type(8))) short short8;
typedef __attribute__((ext_vector_type(4))) float f32x4;

__device__ __forceinline__ unsigned int pkbf(float x, float y) {
    union { __hip_bfloat162 h; unsigned int u; } cv;
    cv.h = __float22bfloat162_rn(make_float2(x, y));
    return cv.u;
}

__device__ __forceinline__ float tanh_fast(float x) {
    return 1.f - 2.f / (1.f + __expf(2.f * x));
}
__device__ __forceinline__ float sigm_(float x) { return 1.f / (1.f + __expf(-x)); }

// ---------------------------------------------------------------------------
// bf16 MFMA GEMM core, 128x128 tile, BK=32, DOUBLE-BUFFERED LDS with
// register prefetch (one barrier per K-iter). fp32->bf16 fused in staging.
// XOR-swizzled 16B chunks -> only free 2-way LDS conflicts.
// ---------------------------------------------------------------------------
__device__ __forceinline__ void mm_core(const float* __restrict__ Abm, int lda,
                                        const float* __restrict__ Wbn, int ldw,
                                        int K, f32x4 acc[4][4])
{
    __shared__ unsigned int As[2][2048];   // per buf: 128 rows x 32 bf16
    __shared__ unsigned int Ws[2][2048];

    const int t = threadIdx.x;
    const int srow = t >> 3, sub = t & 7;
    const int half = sub & 1;
    const int csw = (sub >> 1) ^ ((srow >> 1) & 3);
    int sidx[4];
    const float* pa[4];
    const float* pw[4];
#pragma unroll
    for (int i = 0; i < 4; ++i) {
        int row = srow + 32 * i;
        sidx[i] = row * 16 + csw * 4 + half * 2;
        pa[i] = Abm + (size_t)row * lda + sub * 4;
        pw[i] = Wbn + (size_t)row * ldw + sub * 4;
    }
    const int w = t >> 6, lane = t & 63;
    const int m0 = (w >> 1) * 64, n0 = (w & 1) * 64;
    const int lrow = lane & 15, quad = lane >> 4;
    int aidx[4], widx[4];
#pragma unroll
    for (int i = 0; i < 4; ++i) {
        int ra = m0 + i * 16 + lrow;
        aidx[i] = ra * 16 + ((quad ^ ((ra >> 1) & 3)) << 2);
        int rw = n0 + i * 16 + lrow;
        widx[i] = rw * 16 + ((quad ^ ((rw >> 1) & 3)) << 2);
    }

    float4 ra4[4], rw4[4];
#define MMC_LOAD() do { _Pragma("unroll") for (int i = 0; i < 4; ++i) { \
        ra4[i] = *(const float4*)pa[i]; rw4[i] = *(const float4*)pw[i]; \
        pa[i] += 32; pw[i] += 32; } } while (0)
#define MMC_STORE(buf) do { _Pragma("unroll") for (int i = 0; i < 4; ++i) { \
        *(uint2*)(As[buf] + sidx[i]) = make_uint2(pkbf(ra4[i].x, ra4[i].y), pkbf(ra4[i].z, ra4[i].w)); \
        *(uint2*)(Ws[buf] + sidx[i]) = make_uint2(pkbf(rw4[i].x, rw4[i].y), pkbf(rw4[i].z, rw4[i].w)); } } while (0)

    const int n = K >> 5;                  // all call sites have K >= 256
    MMC_LOAD();
    MMC_STORE(0);
    MMC_LOAD();
    for (int k = 0; k < n; ++k) {
        __syncthreads();                   // buf k&1 fully staged; other buf free
        short8 af[4], wf[4];
#pragma unroll
        for (int i = 0; i < 4; ++i) {
            af[i] = *(const short8*)(As[k & 1] + aidx[i]);
            wf[i] = *(const short8*)(Ws[k & 1] + widx[i]);
        }
        if (k + 1 < n) {
            MMC_STORE((k + 1) & 1);        // other buffer: safe post-barrier
            if (k + 2 < n) MMC_LOAD();     // issue next global loads early
        }
#pragma unroll
        for (int mt = 0; mt < 4; ++mt)
#pragma unroll
            for (int nt = 0; nt < 4; ++nt)
                acc[mt][nt] = __builtin_amdgcn_mfma_f32_16x16x32_bf16(
                    af[mt], wf[nt], acc[mt][nt], 0, 0, 0);
    }
#undef MMC_LOAD
#undef MMC_STORE
}

__device__ __forceinline__ void mm_store(f32x4 acc[4][4], float* __restrict__ Cbm,
                                         int ldc, int bn, const float* __restrict__ bias)
{
    const int t = threadIdx.x;
    const int w = t >> 6, lane = t & 63;
    const int m0 = (w >> 1) * 64, n0 = (w & 1) * 64;
    const int lrow = lane & 15, quad = lane >> 4;
#pragma unroll
    for (int nt = 0; nt < 4; ++nt) {
        int col = bn + n0 + nt * 16 + lrow;
        float bv = bias ? bias[col] : 0.f;
#pragma unroll
        for (int mt = 0; mt < 4; ++mt) {
            int rbase = m0 + mt * 16 + quad * 4;
#pragma unroll
            for (int r = 0; r < 4; ++r)
                Cbm[(size_t)(rbase + r) * ldc + col] = acc[mt][nt][r] + bv;
        }
    }
}

// Fused attention-logit epilogue: lpart[bn_tile][row] = sum_a tanh(...)*wa[a]
__device__ __forceinline__ void attn_epilogue(
    f32x4 acc[4][4], int bm, int bn, int M, int L,
    const float* __restrict__ base, const float* __restrict__ base2,
    const float* __restrict__ wbias, const float* __restrict__ wa,
    float sign, float* __restrict__ lpart)
{
    __shared__ float lsum[2][128];
    const int t = threadIdx.x;
    const int w = t >> 6, lane = t & 63;
    const int m0 = (w >> 1) * 64, n0 = (w & 1) * 64;
    const int lrow = lane & 15, quad = lane >> 4;
    float wav[4], wbv[4];
    int colv[4];
#pragma unroll
    for (int nt = 0; nt < 4; ++nt) {
        colv[nt] = bn + n0 + nt * 16 + lrow;
        wav[nt] = wa[colv[nt]];
        wbv[nt] = wbias ? wbias[colv[nt]] : 0.f;
    }
#pragma unroll
    for (int mt = 0; mt < 4; ++mt) {
#pragma unroll
        for (int r = 0; r < 4; ++r) {
            int rl = m0 + mt * 16 + quad * 4 + r;
            int row = bm + rl;
            int b = row / L;
            const float* bp = base + (size_t)b * A_;
            const float* bp2 = base2 ? base2 + (size_t)b * A_ : nullptr;
            float s = 0.f;
#pragma unroll
            for (int nt = 0; nt < 4; ++nt) {
                float v = bp[colv[nt]] + wbv[nt] + sign * acc[mt][nt][r];
                if (bp2) v += bp2[colv[nt]];
                s += tanh_fast(v) * wav[nt];
            }
            s += __shfl_xor(s, 1);
            s += __shfl_xor(s, 2);
            s += __shfl_xor(s, 4);
            s += __shfl_xor(s, 8);
            if (lrow == 0) lsum[w & 1][rl] = s;
        }
    }
    __syncthreads();
    if (t < 128)
        lpart[(size_t)(bn >> 7) * M + bm + t] = lsum[0][t] + lsum[1][t];
}

// ---------------------------------------------------------------------------
// GEMM kernels
// ---------------------------------------------------------------------------
struct Seg8 { const float* A[8]; const float* W[8]; int lda[8]; int ldw[8]; };

// K-segmented split-K GEMM (LSTM gates): partials to Cbase + z*zstride
__global__ __launch_bounds__(256) void mm_seg(Seg8 s, float* __restrict__ Cbase,
                                              int ldc, int kchunk, int zstride)
{
    int z = blockIdx.z;
    int bm = blockIdx.y * 128, bn = blockIdx.x * 128;
    f32x4 acc[4][4];
#pragma unroll
    for (int i = 0; i < 4; ++i)
#pragma unroll
        for (int j = 0; j < 4; ++j) acc[i][j] = (f32x4)0.f;
    mm_core(s.A[z] + (size_t)bm * s.lda[z], s.lda[z],
            s.W[z] + (size_t)bn * s.ldw[z], s.ldw[z], kchunk, acc);
    mm_store(acc, Cbase + (size_t)z * zstride + (size_t)bm * ldc, ldc, bn, nullptr);
}

// batched small GEMMs (M=256, N=512, K=1024, lda=ldw=1024, ldc=512)
struct Jobs4 { const float* A[4]; const float* W[4]; const float* bias[4]; float* C[4]; };
__global__ __launch_bounds__(256) void mm_jobs(Jobs4 p, int K)
{
    int z = blockIdx.z;
    int bm = blockIdx.y * 128, bn = blockIdx.x * 128;
    f32x4 acc[4][4];
#pragma unroll
    for (int i = 0; i < 4; ++i)
#pragma unroll
        for (int j = 0; j < 4; ++j) acc[i][j] = (f32x4)0.f;
    mm_core(p.A[z] + (size_t)bm * 1024, 1024, p.W[z] + (size_t)bn * 1024, 1024, K, acc);
    mm_store(acc, p.C[z] + (size_t)bm * 512, 512, bn, p.bias[z]);
}

// GEMM + fused tanh-logit reduction (no C write at all)
__global__ __launch_bounds__(256) void mm_fused_attn(
    const float* __restrict__ A, int lda, const float* __restrict__ W, int ldw, int K,
    const float* __restrict__ base, const float* __restrict__ base2,
    const float* __restrict__ wbias, const float* __restrict__ wa,
    float sign, int M, int L, float* __restrict__ lpart)
{
    int bm = blockIdx.y * 128, bn = blockIdx.x * 128;
    f32x4 acc[4][4];
#pragma unroll
    for (int i = 0; i < 4; ++i)
#pragma unroll
        for (int j = 0; j < 4; ++j) acc[i][j] = (f32x4)0.f;
    mm_core(A + (size_t)bm * lda, lda, W + (size_t)bn * ldw, ldw, K, acc);
    attn_epilogue(acc, bm, bn, M, L, base, base2, wbias, wa, sign, lpart);
}

// ---------------------------------------------------------------------------
// pointwise kernels
// ---------------------------------------------------------------------------
__global__ __launch_bounds__(256) void attn_logits_sp(
    const float* __restrict__ base, const float* __restrict__ proj,
    const float* __restrict__ wa, float* __restrict__ logits)
{
    int idx = blockIdx.x * 4 + (threadIdx.x >> 6);   // b*64+l
    int lane = threadIdx.x & 63;
    int b = idx >> 6;
    const f32x4* p = (const f32x4*)(proj + (size_t)idx * A_);
    const f32x4* bs = (const f32x4*)(base + (size_t)b * A_);
    const f32x4* wv = (const f32x4*)wa;
    float acc = 0.f;
#pragma unroll
    for (int i = 0; i < 2; ++i) {
        int a = i * 64 + lane;
        f32x4 pv = p[a], bv = bs[a], w4 = wv[a];
#pragma unroll
        for (int j = 0; j < 4; ++j) acc += tanh_fast(bv[j] + pv[j]) * w4[j];
    }
#pragma unroll
    for (int off = 32; off > 0; off >>= 1) acc += __shfl_xor(acc, off);
    if (lane == 0) logits[idx] = acc;
}

// softmax over L (<=64) per group, summing np logit partials
__global__ __launch_bounds__(256) void softmax_part(
    const float* __restrict__ lpart, int np, int M, int L, float* __restrict__ attw)
{
    int grp = blockIdx.x * 4 + (threadIdx.x >> 6);
    int lane = threadIdx.x & 63;
    int row = grp * L + lane;
    float v = -INFINITY;
    if (lane < L) {
        float s = 0.f;
        for (int p = 0; p < np; ++p) s += lpart[(size_t)p * M + row];
        v = s;
    }
    float m = v;
#pragma unroll
    for (int off = 32; off > 0; off >>= 1) m = fmaxf(m, __shfl_xor(m, off));
    float e = (lane < L) ? __expf(v - m) : 0.f;
    float s = e;
#pragma unroll
    for (int off = 32; off > 0; off >>= 1) s += __shfl_xor(s, off);
    if (lane < L) attw[row] = e / s;
}

// out[b,:] = sum_l w[b,l] * V[b,l,:]
__global__ void ws_one(const float* __restrict__ wgt, const float* __restrict__ V,
                       float* __restrict__ out)
{
    int idx = blockIdx.x * blockDim.x + threadIdx.x;   // B*256 (float4 lanes)
    int b = idx >> 8, d4 = idx & 255;
    const f32x4* vp = (const f32x4*)(V + (size_t)b * L_ * R_) + d4;
    const float* wp = wgt + b * L_;
    f32x4 acc = (f32x4)0.f;
    for (int l = 0; l < L_; ++l) acc += wp[l] * vp[(size_t)l * 256];
    ((f32x4*)out)[idx] = acc;
}

// single pass over roi: out1 = sum w1*V ; out2 = ctx - sum w2*V
__global__ void ws_dual(const float* __restrict__ w1, const float* __restrict__ w2,
                        const float* __restrict__ V, const float* __restrict__ ctx,
                        float* __restrict__ out1, float* __restrict__ out2)
{
    int idx = blockIdx.x * blockDim.x + threadIdx.x;
    int b = idx >> 8, d4 = idx & 255;
    const f32x4* vp = (const f32x4*)(V + (size_t)b * L_ * R_) + d4;
    const float* p1 = w1 + b * L_;
    const float* p2 = w2 + b * L_;
    f32x4 a1 = (f32x4)0.f, a2 = (f32x4)0.f;
    for (int l = 0; l < L_; ++l) {
        f32x4 v = vp[(size_t)l * 256];
        a1 += p1[l] * v;
        a2 += p2[l] * v;
    }
    ((f32x4*)out1)[idx] = a1;
    ((f32x4*)out2)[idx] = ((const f32x4*)ctx)[idx] - a2;
}

__global__ void ws_out_k(const float* __restrict__ wgt, const float* __restrict__ f3,
                         float* __restrict__ out)
{
    int idx = blockIdx.x * blockDim.x + threadIdx.x;   // B*256
    int b = idx >> 8, d4 = idx & 255;
    const f32x4* fp = (const f32x4*)f3;
    f32x4 acc = (f32x4)0.f;
#pragma unroll
    for (int j = 0; j < 3; ++j)
        acc += wgt[b * 3 + j] * fp[(size_t)(b * 3 + j) * 256 + d4];
    ((f32x4*)out)[idx] = acc;
}

__global__ void build_feats3(const float* __restrict__ sf, const float* __restrict__ cf,
                             const float* __restrict__ fc, float* __restrict__ f3)
{
    int idx = blockIdx.x * blockDim.x + threadIdx.x;   // B*3*256
    int d4 = idx & 255;
    int tt = idx >> 8;
    int j = tt % 3, b = tt / 3;
    const float* src = (j == 0) ? sf : (j == 1) ? cf : fc;
    ((f32x4*)f3)[idx] = ((const f32x4*)(src + (size_t)b * R_))[d4];
}

// LSTM pointwise summing P split-K partials + both biases (float4)
__global__ void lstm_pw(const float* __restrict__ gp, int P,
                        const float* __restrict__ b_ih, const float* __restrict__ b_hh,
                        const float* __restrict__ c_prev,
                        float* __restrict__ h_out, float* __restrict__ h_out2,
                        float* __restrict__ c_out)
{
    int idx = blockIdx.x * blockDim.x + threadIdx.x;   // B*256
    int b = idx >> 8, r4 = idx & 255;
    f32x4 g[4];
#pragma unroll
    for (int gi = 0; gi < 4; ++gi) {
        int o = gi * 256 + r4;
        f32x4 s = ((const f32x4*)b_ih)[o] + ((const f32x4*)b_hh)[o];
        for (int p = 0; p < P; ++p)
            s += ((const f32x4*)(gp + (size_t)p * B_ * 4096 + (size_t)b * 4096))[o];
        g[gi] = s;
    }
    f32x4 cp = ((const f32x4*)c_prev)[idx];
    f32x4 c2, h2;
#pragma unroll
    for (int j = 0; j < 4; ++j) {
        float cc = sigm_(g[1][j]) * cp[j] + sigm_(g[0][j]) * tanh_fast(g[2][j]);
        c2[j] = cc;
        h2[j] = sigm_(g[3][j]) * tanh_fast(cc);
    }
    ((f32x4*)c_out)[idx] = c2;
    ((f32x4*)h_out)[idx] = h2;
    if (h_out2) ((f32x4*)h_out2)[idx] = h2;
}

// ---------------------------------------------------------------------------
extern "C" void kernel_launch(void* const* d_in, const int* in_sizes, int n_in,
                              void* d_out, int out_size, void* d_ws, size_t ws_size,
                              hipStream_t stream)
{
    const float* xt      = (const float*)d_in[0];
    const float* fc      = (const float*)d_in[1];
    const float* roi     = (const float*)d_in[2];
    const float* p_roi   = (const float*)d_in[3];
    const float* ctxf    = (const float*)d_in[4];
    const float* sh      = (const float*)d_in[5];
    const float* sc      = (const float*)d_in[6];
    const float* W_ih_v  = (const float*)d_in[7];
    const float* W_hh_v  = (const float*)d_in[8];
    const float* b_ih_v  = (const float*)d_in[9];
    const float* b_hh_v  = (const float*)d_in[10];
    const float* W_ih_l  = (const float*)d_in[11];
    const float* W_hh_l  = (const float*)d_in[12];
    const float* b_ih_l  = (const float*)d_in[13];
    const float* b_hh_l  = (const float*)d_in[14];
    const float* sp_wh_w = (const float*)d_in[15];
    const float* sp_wh_b = (const float*)d_in[16];
    const float* sp_wa_w = (const float*)d_in[17];
    const float* ctx_wh_w= (const float*)d_in[19];
    const float* ctx_wh_b= (const float*)d_in[20];
    const float* ctx_wv_w= (const float*)d_in[21];
    const float* ctx_wv_b= (const float*)d_in[22];
    const float* ctx_wa_w= (const float*)d_in[23];
    const float* cmp_wh_w= (const float*)d_in[25];
    const float* cmp_wh_b= (const float*)d_in[26];
    const float* cmp_wv_w= (const float*)d_in[27];
    const float* cmp_wv_b= (const float*)d_in[28];
    const float* cmp_wa_w= (const float*)d_in[29];
    const float* out_wv_w= (const float*)d_in[31];
    const float* out_wv_b= (const float*)d_in[32];
    const float* out_wh_w= (const float*)d_in[33];
    const float* out_wh_b= (const float*)d_in[34];
    const float* out_wa_w= (const float*)d_in[35];

    float* out = (float*)d_out;
    float* h_vis    = out + BR;
    float* h_lang   = out;
    float* h_lang2  = out + 2 * BR;
    float* c_vis    = out + 3 * BR;
    float* c_lang   = out + 4 * BR;
    float* out_feats= out + 5 * BR;

    float* ws = (float*)d_ws;
    float* gates      = ws;                                  // 8 * 1048576
    float* hproj4     = gates + (size_t)8 * B_ * 4096;       // 4 * 131072
    float* base_cmp2  = hproj4 + (size_t)4 * B_ * A_;        // 131072
    float* lpart      = base_cmp2 + (size_t)B_ * A_;         // 4*16384
    float* lpart_out  = lpart + 4 * 16384;                   // 4*768
    float* logits_sp  = lpart_out + 4 * 768;                 // 16384
    float* attw_sp    = logits_sp + 16384;
    float* attw_ctx   = attw_sp + 16384;
    float* attw_cmp   = attw_ctx + 16384;
    float* attw_out   = attw_cmp + 16384;                    // 768
    float* single_feat= attw_out + 768;                      // B*R
    float* context_feat = single_feat + BR;
    float* comp_feat  = context_feat + BR;
    float* feats3     = comp_feat + BR;                      // 3*B*R

    float* hp0 = hproj4;
    float* hp1 = hproj4 + (size_t)B_ * A_;
    float* hp2 = hproj4 + (size_t)2 * B_ * A_;
    float* hp3 = hproj4 + (size_t)3 * B_ * A_;

    const dim3 blk(256);
    const int ZST = B_ * 4096;

    // ---- visual LSTM: K-concat [prev_h|fc|xt] (W_ih_v) + h0 (W_hh_v), 8x512 split-K
    {
        Seg8 s;
        s.A[0] = sh + BR;       s.W[0] = W_ih_v;          s.lda[0] = 1024; s.ldw[0] = 3072;
        s.A[1] = sh + BR + 512; s.W[1] = W_ih_v + 512;    s.lda[1] = 1024; s.ldw[1] = 3072;
        s.A[2] = fc;            s.W[2] = W_ih_v + 1024;   s.lda[2] = 1024; s.ldw[2] = 3072;
        s.A[3] = fc + 512;      s.W[3] = W_ih_v + 1536;   s.lda[3] = 1024; s.ldw[3] = 3072;
        s.A[4] = xt;            s.W[4] = W_ih_v + 2048;   s.lda[4] = 1024; s.ldw[4] = 3072;
        s.A[5] = xt + 512;      s.W[5] = W_ih_v + 2560;   s.lda[5] = 1024; s.ldw[5] = 3072;
        s.A[6] = sh;            s.W[6] = W_hh_v;          s.lda[6] = 1024; s.ldw[6] = 1024;
        s.A[7] = sh + 512;      s.W[7] = W_hh_v + 512;    s.lda[7] = 1024; s.ldw[7] = 1024;
        mm_seg<<<dim3(32, 2, 8), blk, 0, stream>>>(s, gates, 4096, 512, ZST);
    }
    lstm_pw<<<dim3(B_), blk, 0, stream>>>(gates, 8, b_ih_v, b_hh_v, sc, h_vis, nullptr, c_vis);

    // ---- 4 h_vis projections (with bias) ----
    {
        Jobs4 p;
        p.A[0] = h_vis; p.W[0] = sp_wh_w;  p.bias[0] = sp_wh_b;  p.C[0] = hp0;
        p.A[1] = h_vis; p.W[1] = ctx_wh_w; p.bias[1] = ctx_wh_b; p.C[1] = hp1;
        p.A[2] = h_vis; p.W[2] = cmp_wh_w; p.bias[2] = cmp_wh_b; p.C[2] = hp2;
        p.A[3] = h_vis; p.W[3] = out_wh_w; p.bias[3] = out_wh_b; p.C[3] = hp3;
        mm_jobs<<<dim3(4, 2, 4), blk, 0, stream>>>(p, 1024);
    }

    // ---- SingleSP ----
    attn_logits_sp<<<dim3(B_ * L_ / 4), blk, 0, stream>>>(hp0, p_roi, sp_wa_w, logits_sp);
    softmax_part<<<dim3(64), blk, 0, stream>>>(logits_sp, 1, 16384, 64, attw_sp);

    // ---- ContextSP: fused GEMM+logits (no proj materialization) ----
    mm_fused_attn<<<dim3(4, 128), blk, 0, stream>>>(ctxf, 1024, ctx_wv_w, 1024, 1024,
                                                    hp1, nullptr, ctx_wv_b, ctx_wa_w,
                                                    1.f, 16384, 64, lpart);
    softmax_part<<<dim3(64), blk, 0, stream>>>(lpart, 4, 16384, 64, attw_ctx);
    ws_one<<<dim3(B_), blk, 0, stream>>>(attw_ctx, ctxf, context_feat);

    // ---- CompSP: base_cmp2 = ctx_feat@cmp_wv^T + b ; logits = tanh(base - roi@W)
    {
        Jobs4 p;
        p.A[0] = p.A[1] = p.A[2] = p.A[3] = context_feat;
        p.W[0] = p.W[1] = p.W[2] = p.W[3] = cmp_wv_w;
        p.bias[0] = p.bias[1] = p.bias[2] = p.bias[3] = cmp_wv_b;
        p.C[0] = p.C[1] = p.C[2] = p.C[3] = base_cmp2;
        mm_jobs<<<dim3(4, 2, 1), blk, 0, stream>>>(p, 1024);
    }
    mm_fused_attn<<<dim3(4, 128), blk, 0, stream>>>(roi, 1024, cmp_wv_w, 1024, 1024,
                                                    hp2, base_cmp2, nullptr, cmp_wa_w,
                                                    -1.f, 16384, 64, lpart);
    softmax_part<<<dim3(64), blk, 0, stream>>>(lpart, 4, 16384, 64, attw_cmp);
    // single pass over roi: single_feat and comp_feat (= ctx - sum w*roi)
    ws_dual<<<dim3(B_), blk, 0, stream>>>(attw_sp, attw_cmp, roi, context_feat,
                                          single_feat, comp_feat);

    // ---- OutputSP ----
    build_feats3<<<dim3(B_ * 3), blk, 0, stream>>>(single_feat, comp_feat, fc, feats3);
    mm_fused_attn<<<dim3(4, 6), blk, 0, stream>>>(feats3, 1024, out_wv_w, 1024, 1024,
                                                  hp3, nullptr, out_wv_b, out_wa_w,
                                                  1.f, 768, 3, lpart_out);
    softmax_part<<<dim3(64), blk, 0, stream>>>(lpart_out, 4, 768, 3, attw_out);
    ws_out_k<<<dim3(B_), blk, 0, stream>>>(attw_out, feats3, out_feats);

    // ---- language LSTM: K-concat [out_feats|h_vis] (W_ih_l) + h1 (W_hh_l), 6x512
    {
        Seg8 s;
        s.A[0] = out_feats;       s.W[0] = W_ih_l;        s.lda[0] = 1024; s.ldw[0] = 2048;
        s.A[1] = out_feats + 512; s.W[1] = W_ih_l + 512;  s.lda[1] = 1024; s.ldw[1] = 2048;
        s.A[2] = h_vis;           s.W[2] = W_ih_l + 1024; s.lda[2] = 1024; s.ldw[2] = 2048;
        s.A[3] = h_vis + 512;     s.W[3] = W_ih_l + 1536; s.lda[3] = 1024; s.ldw[3] = 2048;
        s.A[4] = sh + BR;         s.W[4] = W_hh_l;        s.lda[4] = 1024; s.ldw[4] = 1024;
        s.A[5] = sh + BR + 512;   s.W[5] = W_hh_l + 512;  s.lda[5] = 1024; s.ldw[5] = 1024;
        s.A[6] = s.A[5];          s.W[6] = s.W[5];        s.lda[6] = 1024; s.ldw[6] = 1024;
        s.A[7] = s.A[5];          s.W[7] = s.W[5];        s.lda[7] = 1024; s.ldw[7] = 1024;
        mm_seg<<<dim3(32, 2, 6), blk, 0, stream>>>(s, gates, 4096, 512, ZST);
    }
    lstm_pw<<<dim3(B_), blk, 0, stream>>>(gates, 6, b_ih_l, b_hh_l, sc + BR,
                                          h_lang, h_lang2, c_lang);
}